// Round 1
// baseline (264.840 us; speedup 1.0000x reference)
//
#include <hip/hip_runtime.h>
#include <math.h>

#define TT 64
#define NN 64
#define TS 64
#define CC 512
#define NEG (-1e30f)

// output offsets (floats)
#define OUT0 0                    // emissions (64,64,64)
#define OUT1 262144               // gamma     (64,64,64)
#define OUT2 524288               // controls  (63,64,64,2)
#define OUT3 1040384              // read      (63,64,64)
#define OUT4 1298432              // write     (63,64,64)

__device__ __forceinline__ float lse2(float a, float b) {
    float m = fmaxf(a, b);
    float d = fminf(a, b) - m;          // <= 0 (0 if equal incl. both NEG)
    return m + log1pf(__expf(d));
}

// ---------------- Kernel A: gate projection + controls + passthrough ----------------
__global__ __launch_bounds__(256) void gate_kernel(
    const float* __restrict__ x, const float* __restrict__ em,
    const float* __restrict__ w, const float* __restrict__ bptr,
    float* __restrict__ out, float* __restrict__ c0_ws, float* __restrict__ c1_ws)
{
    const int lane  = threadIdx.x & 63;
    const int wave  = (blockIdx.x * blockDim.x + threadIdx.x) >> 6;
    const int nwav  = (gridDim.x * blockDim.x) >> 6;
    const float bias = bptr[0];
    // per-lane weight fragment: lane covers c = 4*lane..4*lane+3 and 256+4*lane..
    const float4 wa = ((const float4*)w)[lane];
    const float4 wb = ((const float4*)w)[lane + 64];
    const int R = TT * NN * TS;

    for (int r = wave; r < R; r += nwav) {
        const float4* xr = (const float4*)(x + (size_t)r * CC);
        float4 xa = xr[lane];
        float4 xb = xr[lane + 64];
        float s = xa.x*wa.x + xa.y*wa.y + xa.z*wa.z + xa.w*wa.w
                + xb.x*wb.x + xb.y*wb.y + xb.z*wb.z + xb.w*wb.w;
        #pragma unroll
        for (int off = 32; off; off >>= 1) s += __shfl_xor(s, off);
        float g  = s + bias;
        // log_sigmoid(g) = -softplus(-g), stable both signs
        float ls = (g >= 0.f) ? -log1pf(__expf(-g)) : (g - log1pf(__expf(g)));
        float c1v = ls - g;
        if (lane == 0) {
            c0_ws[r] = ls;
            int sidx = r & 63;
            c1_ws[r] = (sidx == 63) ? 0.f : c1v;   // masked c1 for M
            int t = r >> 12;                        // r / (NN*TS)
            if (t < TT - 1) {
                float* ctl = out + OUT2 + (size_t)2 * r;
                ctl[0] = ls;                        // raw controls (unmasked)
                ctl[1] = c1v;
            }
        } else if (lane == 1) {
            out[OUT0 + r] = em[r];                  // emissions passthrough
        }
    }
}

// ---------------- Kernel B: forward (alpha, prior) + backward (beta) per n ----------------
__global__ __launch_bounds__(128) void fb_kernel(
    const float* __restrict__ em, const float* __restrict__ c0_ws,
    const float* __restrict__ c1_ws, float* __restrict__ alpha,
    float* __restrict__ beta, float* __restrict__ prior)
{
    const int n    = blockIdx.x;
    const int lane = threadIdx.x & 63;
    const int wv   = threadIdx.x >> 6;

    if (wv == 0) {
        // ---- forward ----
        float a = (lane == 0) ? em[(size_t)n * TS] : NEG;   // alpha0
        alpha[(size_t)n * TS + lane] = a;
        for (int t = 0; t < TT - 1; ++t) {
            size_t base = (size_t)t * NN * TS + (size_t)n * TS;
            float c0 = c0_ws[base + lane];
            float c1 = c1_ws[base + lane];
            // exclusive prefix sum of c0 -> cs
            float incl = c0;
            #pragma unroll
            for (int off = 1; off < 64; off <<= 1) {
                float o = __shfl_up(incl, off);
                if (lane >= off) incl += o;
            }
            float cs = incl - c0;
            // inclusive prefix LSE of (a - cs)
            float v = a - cs;
            #pragma unroll
            for (int off = 1; off < 64; off <<= 1) {
                float o = __shfl_up(v, off);
                if (lane >= off) v = lse2(v, o);
            }
            float e1 = em[base + NN * TS + lane];
            a = c1 + cs + v + e1;
            alpha[base + NN * TS + lane] = a;
        }
        // prior = LSE over lanes of alpha[TT-1]
        float p = a;
        #pragma unroll
        for (int off = 32; off; off >>= 1) p = lse2(p, __shfl_xor(p, off));
        if (lane == 0) prior[n] = p;
    } else {
        // ---- backward ----
        float b = 0.f;
        beta[(size_t)(TT - 1) * NN * TS + (size_t)n * TS + lane] = 0.f;
        for (int t = TT - 2; t >= 0; --t) {
            size_t base = (size_t)t * NN * TS + (size_t)n * TS;
            float c0 = c0_ws[base + lane];
            float c1 = c1_ws[base + lane];
            float incl = c0;
            #pragma unroll
            for (int off = 1; off < 64; off <<= 1) {
                float o = __shfl_up(incl, off);
                if (lane >= off) incl += o;
            }
            float cs = incl - c0;
            float e1 = em[base + NN * TS + lane];
            float wvv = c1 + cs + b + e1;
            // inclusive suffix LSE
            float sfx = wvv;
            #pragma unroll
            for (int off = 1; off < 64; off <<= 1) {
                float o = __shfl_down(sfx, off);
                if (lane < 64 - off) sfx = lse2(sfx, o);
            }
            b = sfx - cs;
            beta[base + lane] = b;
        }
    }
}

// ---------------- Kernel C: gamma / write / read per (t,n) ----------------
__global__ __launch_bounds__(64) void post_kernel(
    const float* __restrict__ em, const float* __restrict__ c0_ws,
    const float* __restrict__ c1_ws, const float* __restrict__ alpha,
    const float* __restrict__ beta, const float* __restrict__ prior,
    float* __restrict__ out)
{
    const int t    = blockIdx.x >> 6;
    const int n    = blockIdx.x & 63;
    const int lane = threadIdx.x;
    size_t base = (size_t)t * NN * TS + (size_t)n * TS;
    float pr = prior[n];
    float a  = alpha[base + lane];
    float bt = beta[base + lane];
    float gm = __expf(a + bt - pr);
    out[OUT1 + base + lane] = gm;
    if (t >= 1) out[OUT4 + base - (size_t)NN * TS + lane] = gm;  // write[t-1] = gamma[t]

    if (t < TT - 1) {
        float c0 = c0_ws[base + lane];
        float c1 = c1_ws[base + lane];
        float incl = c0;
        #pragma unroll
        for (int off = 1; off < 64; off <<= 1) {
            float o = __shfl_up(incl, off);
            if (lane >= off) incl += o;
        }
        float cs = incl - c0;
        float bn = beta[base + NN * TS + lane];
        float e1 = em[base + NN * TS + lane];
        float pu = a - cs;
        float pv = bn + e1 + c1 + cs - pr;
        // LU = inclusive prefix LSE of pu
        float LU = pu;
        #pragma unroll
        for (int off = 1; off < 64; off <<= 1) {
            float o = __shfl_up(LU, off);
            if (lane >= off) LU = lse2(LU, o);
        }
        // LV = inclusive suffix LSE of pv; exclusive via shift by 1
        float LV = pv;
        #pragma unroll
        for (int off = 1; off < 64; off <<= 1) {
            float o = __shfl_down(LV, off);
            if (lane < 64 - off) LV = lse2(LV, o);
        }
        float LVe = __shfl_down(LV, 1);
        if (lane == 63) LVe = NEG;
        out[OUT3 + base + lane] = __expf(LU + LVe);
    }
}

extern "C" void kernel_launch(void* const* d_in, const int* in_sizes, int n_in,
                              void* d_out, int out_size, void* d_ws, size_t ws_size,
                              hipStream_t stream) {
    const float* x  = (const float*)d_in[0];
    const float* em = (const float*)d_in[1];
    const float* w  = (const float*)d_in[2];
    const float* bb = (const float*)d_in[3];
    float* out = (float*)d_out;

    char* ws = (char*)d_ws;
    float* c0_ws  = (float*)(ws);                    // 1 MB
    float* c1_ws  = (float*)(ws + (1u << 20));       // 1 MB
    float* alpha  = (float*)(ws + (2u << 20));       // 1 MB
    float* beta   = (float*)(ws + (3u << 20));       // 1 MB
    float* prior  = (float*)(ws + (4u << 20));       // 256 B

    gate_kernel<<<2048, 256, 0, stream>>>(x, em, w, bb, out, c0_ws, c1_ws);
    fb_kernel<<<NN, 128, 0, stream>>>(em, c0_ws, c1_ws, alpha, beta, prior);
    post_kernel<<<TT * NN, 64, 0, stream>>>(em, c0_ws, c1_ws, alpha, beta, prior, out);
}

// Round 2
// 151.559 us; speedup vs baseline: 1.7474x; 1.7474x over previous
//
#include <hip/hip_runtime.h>
#include <math.h>

#define TT 64
#define NN 64
#define TS 64
#define CC 512
#define NTS (NN * TS)            // 4096
#define NEG (-1e30f)

// output offsets (floats)
#define OUT0 0                    // emissions (64,64,64)
#define OUT1 262144               // gamma     (64,64,64)
#define OUT2 524288               // controls  (63,64,64,2)
#define OUT3 1040384              // read      (63,64,64)
#define OUT4 1298432              // write     (63,64,64)

__device__ __forceinline__ float lse2(float a, float b) {
    float m = fmaxf(a, b);
    float d = fminf(a, b) - m;          // <= 0
    return m + __logf(1.f + __expf(d));
}

// ---------------- Kernel A: gate GEMV only (rows t<63), BW-bound ----------------
__global__ __launch_bounds__(256) void gate_kernel(
    const float* __restrict__ x, const float* __restrict__ w,
    const float* __restrict__ bptr, float* __restrict__ g_ws)
{
    const int lane = threadIdx.x & 63;
    const int wave = (blockIdx.x * blockDim.x + threadIdx.x) >> 6;
    const int nwav = (gridDim.x * blockDim.x) >> 6;
    const float bias = bptr[0];
    const float4 wa = ((const float4*)w)[lane];
    const float4 wb = ((const float4*)w)[lane + 64];
    const int R = (TT - 1) * NTS;       // t=63 rows never used

    for (int r = wave; r < R; r += nwav) {
        const float4* xr = (const float4*)(x + (size_t)r * CC);
        float4 xa = xr[lane];
        float4 xb = xr[lane + 64];
        float s = xa.x*wa.x + xa.y*wa.y + xa.z*wa.z + xa.w*wa.w
                + xb.x*wb.x + xb.y*wb.y + xb.z*wb.z + xb.w*wb.w;
        #pragma unroll
        for (int off = 32; off; off >>= 1) s += __shfl_xor(s, off);
        if (lane == 0) g_ws[r] = s + bias;
    }
}

// ---------------- Kernel B: per-row prep — transcendentals on all lanes ----------------
__global__ __launch_bounds__(256) void prep_kernel(
    const float* __restrict__ em, const float* __restrict__ g_ws,
    float* __restrict__ out, float* __restrict__ cs_ws, float* __restrict__ P_ws)
{
    const int row  = blockIdx.x * 4 + (threadIdx.x >> 6);   // t*64 + n
    const int t    = row >> 6;
    const int lane = threadIdx.x & 63;
    const size_t base = (size_t)row * TS;

    out[OUT0 + base + lane] = em[base + lane];              // emissions passthrough

    if (t < TT - 1) {
        float g  = g_ws[base + lane];
        float ls = (g >= 0.f) ? -log1pf(__expf(-g)) : (g - log1pf(__expf(g)));
        float c1v = ls - g;
        float2 ctl; ctl.x = ls; ctl.y = c1v;
        ((float2*)(out + OUT2))[base + lane] = ctl;         // controls[t,n,s,:]
        float c1m = (lane == TS - 1) ? 0.f : c1v;
        // exclusive prefix sum of ls -> cs
        float incl = ls;
        #pragma unroll
        for (int off = 1; off < 64; off <<= 1) {
            float o = __shfl_up(incl, off);
            if (lane >= off) incl += o;
        }
        float cs = incl - ls;
        cs_ws[base + lane] = cs;
        P_ws[base + lane]  = c1m + cs;
    }
}

// ---------------- Kernel C: forward/backward recursions per n ----------------
__global__ __launch_bounds__(128) void fb_kernel(
    const float* __restrict__ em, const float* __restrict__ cs_ws,
    const float* __restrict__ P_ws, float* __restrict__ alpha,
    float* __restrict__ beta, float* __restrict__ prior)
{
    const int n    = blockIdx.x;
    const int lane = threadIdx.x & 63;
    const int wv   = threadIdx.x >> 6;

    if (wv == 0) {
        // ---- forward ----
        float a = (lane == 0) ? em[(size_t)n * TS] : NEG;
        alpha[(size_t)n * TS + lane] = a;
        size_t base = (size_t)n * TS;
        float cs = cs_ws[base + lane];
        float P  = P_ws[base + lane];
        float e1 = em[base + NTS + lane];
        for (int t = 0; t < TT - 1; ++t) {
            size_t nbase = base + NTS;
            float csn = cs, Pn = P, e1n = e1;
            if (t < TT - 2) {                       // prefetch next step
                csn = cs_ws[nbase + lane];
                Pn  = P_ws[nbase + lane];
                e1n = em[nbase + NTS + lane];
            }
            float v = a - cs;
            #pragma unroll
            for (int off = 1; off < 64; off <<= 1) {
                float o = __shfl_up(v, off);
                if (lane >= off) v = lse2(v, o);
            }
            a = P + v + e1;
            alpha[nbase + lane] = a;
            base = nbase; cs = csn; P = Pn; e1 = e1n;
        }
        float p = a;
        #pragma unroll
        for (int off = 32; off; off >>= 1) p = lse2(p, __shfl_xor(p, off));
        if (lane == 0) prior[n] = p;
    } else {
        // ---- backward ----
        float b = 0.f;
        beta[(size_t)(TT - 1) * NTS + (size_t)n * TS + lane] = 0.f;
        size_t base = (size_t)(TT - 2) * NTS + (size_t)n * TS;
        float cs = cs_ws[base + lane];
        float P  = P_ws[base + lane];
        float e1 = em[base + NTS + lane];
        for (int t = TT - 2; t >= 0; --t) {
            float csn = cs, Pn = P, e1n = e1;
            if (t > 0) {                            // prefetch next step
                csn = cs_ws[base - NTS + lane];
                Pn  = P_ws[base - NTS + lane];
                e1n = em[base + lane];              // em[(t-1)+1] = em[t]
            }
            float sfx = P + b + e1;
            #pragma unroll
            for (int off = 1; off < 64; off <<= 1) {
                float o = __shfl_down(sfx, off);
                if (lane < 64 - off) sfx = lse2(sfx, o);
            }
            b = sfx - cs;
            beta[base + lane] = b;
            base -= NTS; cs = csn; P = Pn; e1 = e1n;
        }
    }
}

// ---------------- Kernel D: gamma / write / read per (t,n) ----------------
__global__ __launch_bounds__(256) void post_kernel(
    const float* __restrict__ em, const float* __restrict__ cs_ws,
    const float* __restrict__ P_ws, const float* __restrict__ alpha,
    const float* __restrict__ beta, const float* __restrict__ prior,
    float* __restrict__ out)
{
    const int row  = blockIdx.x * 4 + (threadIdx.x >> 6);   // t*64 + n
    const int t    = row >> 6;
    const int n    = row & 63;
    const int lane = threadIdx.x & 63;
    const size_t base = (size_t)row * TS;

    float pr = prior[n];
    float a  = alpha[base + lane];
    float bt = beta[base + lane];
    float gm = __expf(a + bt - pr);
    out[OUT1 + base + lane] = gm;
    if (t >= 1) out[OUT4 + base - NTS + lane] = gm;         // write[t-1] = gamma[t]

    if (t < TT - 1) {
        float cs = cs_ws[base + lane];
        float P  = P_ws[base + lane];
        float bn = beta[base + NTS + lane];
        float e1 = em[base + NTS + lane];
        float pu = a - cs;
        float pv = bn + e1 + P - pr;
        float LU = pu;
        #pragma unroll
        for (int off = 1; off < 64; off <<= 1) {
            float o = __shfl_up(LU, off);
            if (lane >= off) LU = lse2(LU, o);
        }
        float LV = pv;
        #pragma unroll
        for (int off = 1; off < 64; off <<= 1) {
            float o = __shfl_down(LV, off);
            if (lane < 64 - off) LV = lse2(LV, o);
        }
        float LVe = __shfl_down(LV, 1);
        if (lane == 63) LVe = NEG;
        out[OUT3 + base + lane] = __expf(LU + LVe);
    }
}

extern "C" void kernel_launch(void* const* d_in, const int* in_sizes, int n_in,
                              void* d_out, int out_size, void* d_ws, size_t ws_size,
                              hipStream_t stream) {
    const float* x  = (const float*)d_in[0];
    const float* em = (const float*)d_in[1];
    const float* w  = (const float*)d_in[2];
    const float* bb = (const float*)d_in[3];
    float* out = (float*)d_out;

    char* ws = (char*)d_ws;
    float* g_ws   = (float*)(ws);                    // 1 MB
    float* cs_ws  = (float*)(ws + (1u << 20));       // 1 MB
    float* P_ws   = (float*)(ws + (2u << 20));       // 1 MB
    float* alpha  = (float*)(ws + (3u << 20));       // 1 MB
    float* beta   = (float*)(ws + (4u << 20));       // 1 MB
    float* prior  = (float*)(ws + (5u << 20));       // 256 B

    gate_kernel<<<2048, 256, 0, stream>>>(x, w, bb, g_ws);
    prep_kernel<<<TT * NN / 4, 256, 0, stream>>>(em, g_ws, out, cs_ws, P_ws);
    fb_kernel<<<NN, 128, 0, stream>>>(em, cs_ws, P_ws, alpha, beta, prior);
    post_kernel<<<TT * NN / 4, 256, 0, stream>>>(em, cs_ws, P_ws, alpha, beta, prior, out);
}

// Round 5
// 117.328 us; speedup vs baseline: 2.2573x; 1.2918x over previous
//
#include <hip/hip_runtime.h>
#include <math.h>

#define TT 64
#define NN 64
#define TS 64
#define CC 512
#define NTS (NN * TS)            // 4096
#define NEG (-1e30f)

// output offsets (floats)
#define OUT0 0                    // emissions (64,64,64)
#define OUT1 262144               // gamma     (64,64,64)
#define OUT2 524288               // controls  (63,64,64,2)
#define OUT3 1040384              // read      (63,64,64)
#define OUT4 1298432              // write     (63,64,64)

typedef float f32x4 __attribute__((ext_vector_type(4)));

__device__ __forceinline__ float lse2(float a, float b) {
    float m = fmaxf(a, b);
    float d = fminf(a, b) - m;          // <= 0 (finite args only: inputs clamped >= NEG)
    return m + __logf(1.f + __expf(d));
}

// ---- DPP helpers: classic GCN wave64 inclusive scans ----
template<int ctrl, int rmask>
__device__ __forceinline__ float dppf(float x, float id) {
    return __int_as_float(__builtin_amdgcn_update_dpp(
        __float_as_int(id), __float_as_int(x), ctrl, rmask, 0xF, false));
}
// row_shr:N = 0x110|N ; row_bcast15 = 0x142 (rows 1,3) ; row_bcast31 = 0x143 (rows 2,3)
__device__ __forceinline__ float scan_max64(float v) {
    v = fmaxf(v, dppf<0x111, 0xF>(v, NEG));
    v = fmaxf(v, dppf<0x112, 0xF>(v, NEG));
    v = fmaxf(v, dppf<0x114, 0xF>(v, NEG));
    v = fmaxf(v, dppf<0x118, 0xF>(v, NEG));
    v = fmaxf(v, dppf<0x142, 0xA>(v, NEG));
    v = fmaxf(v, dppf<0x143, 0xC>(v, NEG));
    return v;
}
__device__ __forceinline__ float scan_sum64(float v) {
    v += dppf<0x111, 0xF>(v, 0.f);
    v += dppf<0x112, 0xF>(v, 0.f);
    v += dppf<0x114, 0xF>(v, 0.f);
    v += dppf<0x118, 0xF>(v, 0.f);
    v += dppf<0x142, 0xA>(v, 0.f);
    v += dppf<0x143, 0xC>(v, 0.f);
    return v;
}
// inclusive prefix-LSE over 64 lanes: global-max rescale + exp + sum-scan + log.
// Clamped to NEG: prefix sums before the argmax can underflow to 0 -> log(0) = -inf,
// and a true -inf downstream makes lse2(-inf,-inf) = NaN. Saturate at -1e30 instead.
__device__ __forceinline__ float scan_lse64(float v) {
    float M = __int_as_float(__builtin_amdgcn_readlane(__float_as_int(scan_max64(v)), 63));
    float p = __expf(v - M);
    float S = scan_sum64(p);
    return fmaxf(__logf(S) + M, NEG);
}

// ---------------- Kernel A: gate GEMV only (rows t<63), BW-bound ----------------
__global__ __launch_bounds__(256) void gate_kernel(
    const float* __restrict__ x, const float* __restrict__ w,
    const float* __restrict__ bptr, float* __restrict__ g_ws)
{
    const int lane = threadIdx.x & 63;
    const int wave = (blockIdx.x * blockDim.x + threadIdx.x) >> 6;
    const int nwav = (gridDim.x * blockDim.x) >> 6;
    const float bias = bptr[0];
    const f32x4 wa = ((const f32x4*)w)[lane];
    const f32x4 wb = ((const f32x4*)w)[lane + 64];
    const int R = (TT - 1) * NTS;       // 258048, even -> pairs always complete

    for (int r0 = 2 * wave; r0 < R; r0 += 2 * nwav) {
        const f32x4* xr0 = (const f32x4*)(x + (size_t)r0 * CC);
        const f32x4* xr1 = xr0 + (CC / 4);
        f32x4 a0 = __builtin_nontemporal_load(&xr0[lane]);
        f32x4 b0 = __builtin_nontemporal_load(&xr0[lane + 64]);
        f32x4 a1 = __builtin_nontemporal_load(&xr1[lane]);
        f32x4 b1 = __builtin_nontemporal_load(&xr1[lane + 64]);
        float s0 = a0.x*wa.x + a0.y*wa.y + a0.z*wa.z + a0.w*wa.w
                 + b0.x*wb.x + b0.y*wb.y + b0.z*wb.z + b0.w*wb.w;
        float s1 = a1.x*wa.x + a1.y*wa.y + a1.z*wa.z + a1.w*wa.w
                 + b1.x*wb.x + b1.y*wb.y + b1.z*wb.z + b1.w*wb.w;
        #pragma unroll
        for (int off = 32; off; off >>= 1) {
            s0 += __shfl_xor(s0, off);
            s1 += __shfl_xor(s1, off);
        }
        if (lane == 0) {
            g_ws[r0]     = s0 + bias;
            g_ws[r0 + 1] = s1 + bias;
        }
    }
}

// ---------------- Kernel B: per-row prep — transcendentals on all lanes ----------------
__global__ __launch_bounds__(256) void prep_kernel(
    const float* __restrict__ em, const float* __restrict__ g_ws,
    float* __restrict__ out, float* __restrict__ cs_ws, float* __restrict__ P_ws)
{
    const int row  = blockIdx.x * 4 + (threadIdx.x >> 6);   // t*64 + n
    const int t    = row >> 6;
    const int lane = threadIdx.x & 63;
    const size_t base = (size_t)row * TS;

    out[OUT0 + base + lane] = em[base + lane];              // emissions passthrough

    if (t < TT - 1) {
        float g  = g_ws[base + lane];
        float ls = (g >= 0.f) ? -log1pf(__expf(-g)) : (g - log1pf(__expf(g)));
        float c1v = ls - g;
        float2 ctl; ctl.x = ls; ctl.y = c1v;
        ((float2*)(out + OUT2))[base + lane] = ctl;         // controls[t,n,s,:]
        float c1m = (lane == TS - 1) ? 0.f : c1v;
        float cs = scan_sum64(ls) - ls;                     // exclusive prefix sum
        cs_ws[base + lane] = cs;
        P_ws[base + lane]  = c1m + cs;
    }
}

// ---------------- Kernel C: forward/backward recursions per n ----------------
__global__ __launch_bounds__(128) void fb_kernel(
    const float* __restrict__ em, const float* __restrict__ cs_ws,
    const float* __restrict__ P_ws, float* __restrict__ alpha,
    float* __restrict__ beta, float* __restrict__ prior)
{
    const int n    = blockIdx.x;
    const int lane = threadIdx.x & 63;
    const int wv   = threadIdx.x >> 6;

    if (wv == 0) {
        // ---- forward: alpha[t+1] = P + prefixLSE(alpha[t]-cs) + e[t+1] ----
        float a = (lane == 0) ? em[(size_t)n * TS] : NEG;
        alpha[(size_t)n * TS + lane] = a;
        size_t base = (size_t)n * TS;
        float cs = cs_ws[base + lane];
        float P  = P_ws[base + lane];
        float e1 = em[base + NTS + lane];
        for (int t = 0; t < TT - 1; ++t) {
            size_t nbase = base + NTS;
            float csn = cs, Pn = P, e1n = e1;
            if (t < TT - 2) {                       // prefetch next step
                csn = cs_ws[nbase + lane];
                Pn  = P_ws[nbase + lane];
                e1n = em[nbase + NTS + lane];
            }
            a = P + scan_lse64(a - cs) + e1;
            alpha[nbase + lane] = a;
            base = nbase; cs = csn; P = Pn; e1 = e1n;
        }
        float p = a;
        #pragma unroll
        for (int off = 32; off; off >>= 1) p = lse2(p, __shfl_xor(p, off));
        if (lane == 0) prior[n] = p;
    } else {
        // ---- backward, lane-reversed so suffix-LSE becomes prefix-LSE ----
        const int rl = 63 - lane;                   // this lane's state index
        float b = 0.f;
        beta[(size_t)(TT - 1) * NTS + (size_t)n * TS + rl] = 0.f;
        size_t base = (size_t)(TT - 2) * NTS + (size_t)n * TS;
        float cs = cs_ws[base + rl];
        float P  = P_ws[base + rl];
        float e1 = em[base + NTS + rl];
        for (int t = TT - 2; t >= 0; --t) {
            float csn = cs, Pn = P, e1n = e1;
            if (t > 0) {                            // prefetch next step
                csn = cs_ws[base - NTS + rl];
                Pn  = P_ws[base - NTS + rl];
                e1n = em[base + rl];                // em[(t-1)+1] = em[t]
            }
            b = scan_lse64(P + b + e1) - cs;        // prefix over lanes = suffix over states
            beta[base + rl] = b;
            base -= NTS; cs = csn; P = Pn; e1 = e1n;
        }
    }
}

// ---------------- Kernel D: gamma / write / read per (t,n) ----------------
__global__ __launch_bounds__(256) void post_kernel(
    const float* __restrict__ em, const float* __restrict__ cs_ws,
    const float* __restrict__ P_ws, const float* __restrict__ alpha,
    const float* __restrict__ beta, const float* __restrict__ prior,
    float* __restrict__ out)
{
    const int row  = blockIdx.x * 4 + (threadIdx.x >> 6);   // t*64 + n
    const int t    = row >> 6;
    const int n    = row & 63;
    const int lane = threadIdx.x & 63;
    const size_t base = (size_t)row * TS;

    float pr = prior[n];
    float a  = alpha[base + lane];
    float bt = beta[base + lane];
    float gm = __expf(a + bt - pr);
    out[OUT1 + base + lane] = gm;
    if (t >= 1) out[OUT4 + base - NTS + lane] = gm;         // write[t-1] = gamma[t]

    if (t < TT - 1) {
        float cs = cs_ws[base + lane];
        float P  = P_ws[base + lane];
        float bn = beta[base + NTS + lane];
        float e1 = em[base + NTS + lane];
        float pu = a - cs;
        float pv = bn + e1 + P - pr;
        float LU = pu;
        #pragma unroll
        for (int off = 1; off < 64; off <<= 1) {
            float o = __shfl_up(LU, off);
            if (lane >= off) LU = lse2(LU, o);
        }
        float LV = pv;
        #pragma unroll
        for (int off = 1; off < 64; off <<= 1) {
            float o = __shfl_down(LV, off);
            if (lane < 64 - off) LV = lse2(LV, o);
        }
        float LVe = __shfl_down(LV, 1);
        if (lane == 63) LVe = NEG;
        out[OUT3 + base + lane] = __expf(LU + LVe);
    }
}

extern "C" void kernel_launch(void* const* d_in, const int* in_sizes, int n_in,
                              void* d_out, int out_size, void* d_ws, size_t ws_size,
                              hipStream_t stream) {
    const float* x  = (const float*)d_in[0];
    const float* em = (const float*)d_in[1];
    const float* w  = (const float*)d_in[2];
    const float* bb = (const float*)d_in[3];
    float* out = (float*)d_out;

    char* ws = (char*)d_ws;
    float* g_ws   = (float*)(ws);                    // 1 MB
    float* cs_ws  = (float*)(ws + (1u << 20));       // 1 MB
    float* P_ws   = (float*)(ws + (2u << 20));       // 1 MB
    float* alpha  = (float*)(ws + (3u << 20));       // 1 MB
    float* beta   = (float*)(ws + (4u << 20));       // 1 MB
    float* prior  = (float*)(ws + (5u << 20));       // 256 B

    gate_kernel<<<2048, 256, 0, stream>>>(x, w, bb, g_ws);
    prep_kernel<<<TT * NN / 4, 256, 0, stream>>>(em, g_ws, out, cs_ws, P_ws);
    fb_kernel<<<NN, 128, 0, stream>>>(em, cs_ws, P_ws, alpha, beta, prior);
    post_kernel<<<TT * NN / 4, 256, 0, stream>>>(em, cs_ws, P_ws, alpha, beta, prior, out);
}

// Round 6
// 117.085 us; speedup vs baseline: 2.2620x; 1.0021x over previous
//
#include <hip/hip_runtime.h>
#include <math.h>

#define TT 64
#define NN 64
#define TS 64
#define CC 512
#define NTS (NN * TS)            // 4096
#define NEG (-1e30f)

// output offsets (floats)
#define OUT0 0                    // emissions (64,64,64)
#define OUT1 262144               // gamma     (64,64,64)
#define OUT2 524288               // controls  (63,64,64,2)
#define OUT3 1040384              // read      (63,64,64)
#define OUT4 1298432              // write     (63,64,64)

typedef float f32x4 __attribute__((ext_vector_type(4)));

__device__ __forceinline__ float lse2(float a, float b) {
    float m = fmaxf(a, b);
    float d = fminf(a, b) - m;          // <= 0 (finite args only: inputs clamped >= NEG)
    return m + __logf(1.f + __expf(d));
}

// ---- DPP helpers: classic GCN wave64 inclusive scans ----
template<int ctrl, int rmask>
__device__ __forceinline__ float dppf(float x, float id) {
    return __int_as_float(__builtin_amdgcn_update_dpp(
        __float_as_int(id), __float_as_int(x), ctrl, rmask, 0xF, false));
}
// row_shr:N = 0x110|N ; row_bcast15 = 0x142 (rows 1,3) ; row_bcast31 = 0x143 (rows 2,3)
__device__ __forceinline__ float scan_max64(float v) {
    v = fmaxf(v, dppf<0x111, 0xF>(v, NEG));
    v = fmaxf(v, dppf<0x112, 0xF>(v, NEG));
    v = fmaxf(v, dppf<0x114, 0xF>(v, NEG));
    v = fmaxf(v, dppf<0x118, 0xF>(v, NEG));
    v = fmaxf(v, dppf<0x142, 0xA>(v, NEG));
    v = fmaxf(v, dppf<0x143, 0xC>(v, NEG));
    return v;
}
__device__ __forceinline__ float scan_sum64(float v) {
    v += dppf<0x111, 0xF>(v, 0.f);
    v += dppf<0x112, 0xF>(v, 0.f);
    v += dppf<0x114, 0xF>(v, 0.f);
    v += dppf<0x118, 0xF>(v, 0.f);
    v += dppf<0x142, 0xA>(v, 0.f);
    v += dppf<0x143, 0xC>(v, 0.f);
    return v;
}
// inclusive prefix-LSE over 64 lanes: global-max rescale + exp + sum-scan + log.
// Clamped to NEG: prefix sums before the argmax can underflow to 0 -> log(0) = -inf,
// and a true -inf downstream makes lse2(-inf,-inf) = NaN. Saturate at -1e30 instead.
__device__ __forceinline__ float scan_lse64(float v) {
    float M = __int_as_float(__builtin_amdgcn_readlane(__float_as_int(scan_max64(v)), 63));
    float p = __expf(v - M);
    float S = scan_sum64(p);
    return fmaxf(__logf(S) + M, NEG);
}

// ---------------- Kernel A: gate GEMV (rows t<63), software-pipelined ----------------
__global__ __launch_bounds__(256) void gate_kernel(
    const float* __restrict__ x, const float* __restrict__ w,
    const float* __restrict__ bptr, float* __restrict__ g_ws)
{
    const int lane = threadIdx.x & 63;
    const int wave = (blockIdx.x * blockDim.x + threadIdx.x) >> 6;
    const int nwav = (gridDim.x * blockDim.x) >> 6;
    const float bias = bptr[0];
    const f32x4 wa = ((const f32x4*)w)[lane];
    const f32x4 wb = ((const f32x4*)w)[lane + 64];
    const int R = (TT - 1) * NTS;       // 258048, even -> pairs always complete
    const int stride = 2 * nwav;

    int r = 2 * wave;                   // every wave has >= 1 pair (2*8192 << R)
    f32x4 A0, B0, A1, B1;
    {
        const f32x4* p0 = (const f32x4*)(x + (size_t)r * CC);
        A0 = __builtin_nontemporal_load(&p0[lane]);
        B0 = __builtin_nontemporal_load(&p0[lane + 64]);
        A1 = __builtin_nontemporal_load(&p0[lane + 128]);
        B1 = __builtin_nontemporal_load(&p0[lane + 192]);
    }
    while (true) {
        int rn = r + stride;
        bool more = rn < R;
        f32x4 C0, D0, C1, D1;
        if (more) {                      // issue next pair BEFORE the reduce chain
            const f32x4* p1 = (const f32x4*)(x + (size_t)rn * CC);
            C0 = __builtin_nontemporal_load(&p1[lane]);
            D0 = __builtin_nontemporal_load(&p1[lane + 64]);
            C1 = __builtin_nontemporal_load(&p1[lane + 128]);
            D1 = __builtin_nontemporal_load(&p1[lane + 192]);
        }
        float s0 = A0.x*wa.x + A0.y*wa.y + A0.z*wa.z + A0.w*wa.w
                 + B0.x*wb.x + B0.y*wb.y + B0.z*wb.z + B0.w*wb.w;
        float s1 = A1.x*wa.x + A1.y*wa.y + A1.z*wa.z + A1.w*wa.w
                 + B1.x*wb.x + B1.y*wb.y + B1.z*wb.z + B1.w*wb.w;
        #pragma unroll
        for (int off = 32; off; off >>= 1) {
            s0 += __shfl_xor(s0, off);
            s1 += __shfl_xor(s1, off);
        }
        if (lane == 0) {
            float2 gv; gv.x = s0 + bias; gv.y = s1 + bias;
            *(float2*)(g_ws + r) = gv;   // r even -> 8B aligned
        }
        if (!more) break;
        A0 = C0; B0 = D0; A1 = C1; B1 = D1;
        r = rn;
    }
}

// ---------------- Kernel B: per-row prep — transcendentals on all lanes ----------------
__global__ __launch_bounds__(256) void prep_kernel(
    const float* __restrict__ em, const float* __restrict__ g_ws,
    float* __restrict__ out, float* __restrict__ cs_ws, float* __restrict__ P_ws)
{
    const int row  = blockIdx.x * 4 + (threadIdx.x >> 6);   // t*64 + n
    const int t    = row >> 6;
    const int lane = threadIdx.x & 63;
    const size_t base = (size_t)row * TS;

    out[OUT0 + base + lane] = em[base + lane];              // emissions passthrough

    if (t < TT - 1) {
        float g  = g_ws[base + lane];
        float ls = (g >= 0.f) ? -log1pf(__expf(-g)) : (g - log1pf(__expf(g)));
        float c1v = ls - g;
        float2 ctl; ctl.x = ls; ctl.y = c1v;
        ((float2*)(out + OUT2))[base + lane] = ctl;         // controls[t,n,s,:]
        float c1m = (lane == TS - 1) ? 0.f : c1v;
        float cs = scan_sum64(ls) - ls;                     // exclusive prefix sum
        cs_ws[base + lane] = cs;
        P_ws[base + lane]  = c1m + cs;
    }
}

// ---------------- Kernel C: forward/backward recursions per n ----------------
__global__ __launch_bounds__(128) void fb_kernel(
    const float* __restrict__ em, const float* __restrict__ cs_ws,
    const float* __restrict__ P_ws, float* __restrict__ alpha,
    float* __restrict__ beta, float* __restrict__ prior)
{
    const int n    = blockIdx.x;
    const int lane = threadIdx.x & 63;
    const int wv   = threadIdx.x >> 6;

    if (wv == 0) {
        // ---- forward: alpha[t+1] = P + prefixLSE(alpha[t]-cs) + e[t+1] ----
        float a = (lane == 0) ? em[(size_t)n * TS] : NEG;
        alpha[(size_t)n * TS + lane] = a;
        size_t base = (size_t)n * TS;
        float cs = cs_ws[base + lane];
        float P  = P_ws[base + lane];
        float e1 = em[base + NTS + lane];
        for (int t = 0; t < TT - 1; ++t) {
            size_t nbase = base + NTS;
            float csn = cs, Pn = P, e1n = e1;
            if (t < TT - 2) {                       // prefetch next step
                csn = cs_ws[nbase + lane];
                Pn  = P_ws[nbase + lane];
                e1n = em[nbase + NTS + lane];
            }
            a = P + scan_lse64(a - cs) + e1;
            alpha[nbase + lane] = a;
            base = nbase; cs = csn; P = Pn; e1 = e1n;
        }
        float p = a;
        #pragma unroll
        for (int off = 32; off; off >>= 1) p = lse2(p, __shfl_xor(p, off));
        if (lane == 0) prior[n] = p;
    } else {
        // ---- backward, lane-reversed so suffix-LSE becomes prefix-LSE ----
        const int rl = 63 - lane;                   // this lane's state index
        float b = 0.f;
        beta[(size_t)(TT - 1) * NTS + (size_t)n * TS + rl] = 0.f;
        size_t base = (size_t)(TT - 2) * NTS + (size_t)n * TS;
        float cs = cs_ws[base + rl];
        float P  = P_ws[base + rl];
        float e1 = em[base + NTS + rl];
        for (int t = TT - 2; t >= 0; --t) {
            float csn = cs, Pn = P, e1n = e1;
            if (t > 0) {                            // prefetch next step
                csn = cs_ws[base - NTS + rl];
                Pn  = P_ws[base - NTS + rl];
                e1n = em[base + rl];                // em[(t-1)+1] = em[t]
            }
            b = scan_lse64(P + b + e1) - cs;        // prefix over lanes = suffix over states
            beta[base + rl] = b;
            base -= NTS; cs = csn; P = Pn; e1 = e1n;
        }
    }
}

// ---------------- Kernel D: gamma / write / read per (t,n), DPP scans ----------------
__global__ __launch_bounds__(256) void post_kernel(
    const float* __restrict__ em, const float* __restrict__ cs_ws,
    const float* __restrict__ P_ws, const float* __restrict__ alpha,
    const float* __restrict__ beta, const float* __restrict__ prior,
    float* __restrict__ out)
{
    const int row  = blockIdx.x * 4 + (threadIdx.x >> 6);   // t*64 + n
    const int t    = row >> 6;
    const int n    = row & 63;
    const int lane = threadIdx.x & 63;
    const size_t base = (size_t)row * TS;

    float pr = prior[n];
    float a  = alpha[base + lane];
    float bt = beta[base + lane];
    float gm = __expf(a + bt - pr);
    out[OUT1 + base + lane] = gm;
    if (t >= 1) out[OUT4 + base - NTS + lane] = gm;         // write[t-1] = gamma[t]

    if (t < TT - 1) {
        float cs = cs_ws[base + lane];
        float P  = P_ws[base + lane];
        float bn = beta[base + NTS + lane];
        float e1 = em[base + NTS + lane];
        float pu = a - cs;
        float pv = bn + e1 + P - pr;
        // LU = inclusive prefix LSE of pu (DPP)
        float LU = scan_lse64(pu);
        // LV = inclusive suffix LSE of pv: reverse lanes, prefix-scan, reverse back
        float rv = __shfl(pv, 63 - lane);
        float LVr = scan_lse64(rv);
        float LV = __shfl(LVr, 63 - lane);
        float LVe = __shfl_down(LV, 1);             // exclusive suffix (j > k)
        if (lane == 63) LVe = NEG;
        out[OUT3 + base + lane] = __expf(LU + LVe);
    }
}

extern "C" void kernel_launch(void* const* d_in, const int* in_sizes, int n_in,
                              void* d_out, int out_size, void* d_ws, size_t ws_size,
                              hipStream_t stream) {
    const float* x  = (const float*)d_in[0];
    const float* em = (const float*)d_in[1];
    const float* w  = (const float*)d_in[2];
    const float* bb = (const float*)d_in[3];
    float* out = (float*)d_out;

    char* ws = (char*)d_ws;
    float* g_ws   = (float*)(ws);                    // 1 MB
    float* cs_ws  = (float*)(ws + (1u << 20));       // 1 MB
    float* P_ws   = (float*)(ws + (2u << 20));       // 1 MB
    float* alpha  = (float*)(ws + (3u << 20));       // 1 MB
    float* beta   = (float*)(ws + (4u << 20));       // 1 MB
    float* prior  = (float*)(ws + (5u << 20));       // 256 B

    gate_kernel<<<2048, 256, 0, stream>>>(x, w, bb, g_ws);
    prep_kernel<<<TT * NN / 4, 256, 0, stream>>>(em, g_ws, out, cs_ws, P_ws);
    fb_kernel<<<NN, 128, 0, stream>>>(em, cs_ws, P_ws, alpha, beta, prior);
    post_kernel<<<TT * NN / 4, 256, 0, stream>>>(em, cs_ws, P_ws, alpha, beta, prior, out);
}